// Round 1
// baseline (584.270 us; speedup 1.0000x reference)
//
#include <hip/hip_runtime.h>
#include <hip/hip_bf16.h>

#define HIDDEN 512
#define ATT    128
#define NB     64
#define SL     2048
#define LN_EPS 1e-3f

typedef __attribute__((ext_vector_type(8))) short short8;
typedef __attribute__((ext_vector_type(4))) short short4v;
typedef __attribute__((ext_vector_type(4))) float f32x4;

__device__ __forceinline__ short f2bf(float f) {
    union { float f; unsigned u; } v; v.f = f;
    unsigned r = v.u + 0x7fffu + ((v.u >> 16) & 1u);   // RNE
    return (short)(r >> 16);
}

__device__ __forceinline__ float tanh_fast(float x) {
    float cx = fminf(fmaxf(x, -15.f), 15.f);
    float e = __expf(2.f * cx);
    return (e - 1.f) * __builtin_amdgcn_rcpf(e + 1.f);
}

// ---- Pass 1: per-batch column sums of hidden (context * L) ----------------
__global__ void ctx_kernel(const float* __restrict__ hidden, float* __restrict__ ctx) {
    int b = blockIdx.y, chunk = blockIdx.x, h = threadIdx.x;  // 512 threads
    const float* p = hidden + ((size_t)b * SL + (size_t)chunk * 256) * HIDDEN + h;
    float s = 0.f;
    #pragma unroll 4
    for (int l = 0; l < 256; ++l) s += p[(size_t)l * HIDDEN];
    atomicAdd(&ctx[b * HIDDEN + h], s);
}

// ---- Pass 2a: u_att[b][a] = (ctx[b]/L) @ U_a ------------------------------
__global__ void uatt_kernel(const float* __restrict__ ctx, const float* __restrict__ U,
                            float* __restrict__ uatt) {
    int b = blockIdx.x, a = threadIdx.x;  // 128 threads
    const float* c = ctx + b * HIDDEN;
    float s = 0.f;
    #pragma unroll 8
    for (int h = 0; h < HIDDEN; ++h) s += c[h] * U[h * ATT + a];
    uatt[b * ATT + a] = s * (1.f / SL);
}

// ---- Pass 2b: scores[b][l] = v . tanh(h @ W + u_att[b]) (MFMA bf16) -------
__launch_bounds__(256)
__global__ void scores_kernel(const float* __restrict__ hidden, const float* __restrict__ W,
                              const float* __restrict__ v_a, const float* __restrict__ uatt,
                              float* __restrict__ scores) {
    __shared__ short As[128 * 32];   // [row][k] bf16
    __shared__ short Ws[128 * 32];   // [n][k]   bf16 (W transposed)
    int t = threadIdx.x;
    int row0 = blockIdx.x * 128;          // 128 rows of (b,l); blocks never straddle b
    int b = row0 >> 11;
    int wave = t >> 6, lane = t & 63, quad = lane >> 4, cb = lane & 15;

    float u_reg[8], v_reg[8];
    #pragma unroll
    for (int nt = 0; nt < 8; ++nt) {
        u_reg[nt] = uatt[b * ATT + nt * 16 + cb];
        v_reg[nt] = v_a[nt * 16 + cb];
    }

    f32x4 acc[2][8];
    #pragma unroll
    for (int mt = 0; mt < 2; ++mt)
        #pragma unroll
        for (int nt = 0; nt < 8; ++nt)
            acc[mt][nt] = (f32x4){0.f, 0.f, 0.f, 0.f};

    for (int k0 = 0; k0 < HIDDEN; k0 += 32) {
        __syncthreads();
        // stage A-tile: 128 rows x 32 k, fp32 -> bf16
        #pragma unroll
        for (int it = 0; it < 4; ++it) {
            int f = t + it * 256;
            int row = f >> 3, kpos = (f & 7) * 4;
            const float4 g = *(const float4*)(hidden + ((size_t)(row0 + row)) * HIDDEN + k0 + kpos);
            short4v s4 = { f2bf(g.x), f2bf(g.y), f2bf(g.z), f2bf(g.w) };
            *(short4v*)(&As[row * 32 + kpos]) = s4;
        }
        // stage W-tile transposed: Ws[n][k] <- W[k0+k][n]
        #pragma unroll
        for (int it = 0; it < 4; ++it) {
            int k = (t >> 5) + it * 8;
            int n4 = (t & 31) * 4;
            const float4 g = *(const float4*)(W + (k0 + k) * ATT + n4);
            Ws[(n4 + 0) * 32 + k] = f2bf(g.x);
            Ws[(n4 + 1) * 32 + k] = f2bf(g.y);
            Ws[(n4 + 2) * 32 + k] = f2bf(g.z);
            Ws[(n4 + 3) * 32 + k] = f2bf(g.w);
        }
        __syncthreads();
        short8 a0 = *(const short8*)(&As[(wave * 32 + cb) * 32 + quad * 8]);
        short8 a1 = *(const short8*)(&As[(wave * 32 + 16 + cb) * 32 + quad * 8]);
        #pragma unroll
        for (int nt = 0; nt < 8; ++nt) {
            short8 bf = *(const short8*)(&Ws[(nt * 16 + cb) * 32 + quad * 8]);
            acc[0][nt] = __builtin_amdgcn_mfma_f32_16x16x32_bf16(a0, bf, acc[0][nt], 0, 0, 0);
            acc[1][nt] = __builtin_amdgcn_mfma_f32_16x16x32_bf16(a1, bf, acc[1][nt], 0, 0, 0);
        }
    }

    // epilogue: score[row] = sum over 128 cols of v[c]*tanh(h_att + u[c])
    #pragma unroll
    for (int mt = 0; mt < 2; ++mt) {
        #pragma unroll
        for (int j = 0; j < 4; ++j) {
            float s = 0.f;
            #pragma unroll
            for (int nt = 0; nt < 8; ++nt)
                s += v_reg[nt] * tanh_fast(acc[mt][nt][j] + u_reg[nt]);
            s += __shfl_xor(s, 1, 16);
            s += __shfl_xor(s, 2, 16);
            s += __shfl_xor(s, 4, 16);
            s += __shfl_xor(s, 8, 16);
            if (cb == 0) {
                int r = row0 + wave * 32 + mt * 16 + quad * 4 + j;
                scores[r] = s;   // flat [b][l] == r
            }
        }
    }
}

// ---- Pass 3: softmax over L, in place in d_out's attn region --------------
__global__ void softmax_kernel(float* __restrict__ attn) {
    int b = blockIdx.x, t = threadIdx.x;  // 256 threads
    float* p = attn + b * SL;
    __shared__ float red[256];
    float v[8];
    float m = -1e30f;
    #pragma unroll
    for (int i = 0; i < 8; ++i) { v[i] = p[t + i * 256]; m = fmaxf(m, v[i]); }
    red[t] = m; __syncthreads();
    for (int s = 128; s > 0; s >>= 1) { if (t < s) red[t] = fmaxf(red[t], red[t + s]); __syncthreads(); }
    m = red[0]; __syncthreads();
    float sum = 0.f;
    #pragma unroll
    for (int i = 0; i < 8; ++i) { v[i] = __expf(v[i] - m); sum += v[i]; }
    red[t] = sum; __syncthreads();
    for (int s = 128; s > 0; s >>= 1) { if (t < s) red[t] += red[t + s]; __syncthreads(); }
    float inv = 1.f / red[0];
    #pragma unroll
    for (int i = 0; i < 8; ++i) p[t + i * 256] = v[i] * inv;
}

// ---- Pass 4: attended[b][h] = sum_l attn[b][l] * hidden[b][l][h] ----------
__global__ void attended_kernel(const float* __restrict__ hidden, const float* __restrict__ attn,
                                float* __restrict__ att_out) {
    int b = blockIdx.y, chunk = blockIdx.x, t = threadIdx.x;  // 256 threads
    const float* hp = hidden + ((size_t)b * SL + (size_t)chunk * 128) * HIDDEN;
    const float* ap = attn + b * SL + chunk * 128;
    float a0 = 0.f, a1 = 0.f;
    for (int l = 0; l < 128; ++l) {
        float w = ap[l];
        a0 += w * hp[(size_t)l * HIDDEN + t];
        a1 += w * hp[(size_t)l * HIDDEN + t + 256];
    }
    atomicAdd(&att_out[b * HIDDEN + t], a0);
    atomicAdd(&att_out[b * HIDDEN + t + 256], a1);
}

// ---- Pass 5: LayerNorm over H ---------------------------------------------
__global__ void ln_kernel(const float* __restrict__ att, const float* __restrict__ gamma,
                          const float* __restrict__ beta, float* __restrict__ out) {
    int b = blockIdx.x, t = threadIdx.x;  // 256 threads
    float x0 = att[b * HIDDEN + t], x1 = att[b * HIDDEN + t + 256];
    __shared__ float rs[256], rq[256];
    rs[t] = x0 + x1; rq[t] = x0 * x0 + x1 * x1;
    __syncthreads();
    for (int s = 128; s > 0; s >>= 1) {
        if (t < s) { rs[t] += rs[t + s]; rq[t] += rq[t + s]; }
        __syncthreads();
    }
    float mean = rs[0] * (1.f / HIDDEN);
    float var = rq[0] * (1.f / HIDDEN) - mean * mean;
    float r = rsqrtf(var + LN_EPS);
    out[b * HIDDEN + t]       = (x0 - mean) * r * gamma[t] + beta[t];
    out[b * HIDDEN + t + 256] = (x1 - mean) * r * gamma[t + 256] + beta[t + 256];
}

extern "C" void kernel_launch(void* const* d_in, const int* in_sizes, int n_in,
                              void* d_out, int out_size, void* d_ws, size_t ws_size,
                              hipStream_t stream) {
    const float* hidden = (const float*)d_in[0];
    const float* W      = (const float*)d_in[1];
    const float* U      = (const float*)d_in[2];
    const float* v_a    = (const float*)d_in[3];
    const float* gamma  = (const float*)d_in[4];
    const float* beta   = (const float*)d_in[5];

    float* out  = (float*)d_out;          // [64][512]
    float* attn = out + NB * HIDDEN;      // [64][2048] (scores -> softmax in place)

    float* ctx     = (float*)d_ws;              // [64][512]
    float* att_out = ctx + NB * HIDDEN;         // [64][512]
    float* uatt    = att_out + NB * HIDDEN;     // [64][128]

    // zero the two atomically-accumulated buffers (ws is poisoned each call)
    hipMemsetAsync(d_ws, 0, 2 * NB * HIDDEN * sizeof(float), stream);

    ctx_kernel<<<dim3(8, NB), 512, 0, stream>>>(hidden, ctx);
    uatt_kernel<<<NB, ATT, 0, stream>>>(ctx, U, uatt);
    scores_kernel<<<(NB * SL) / 128, 256, 0, stream>>>(hidden, W, v_a, uatt, attn);
    softmax_kernel<<<NB, 256, 0, stream>>>(attn);
    attended_kernel<<<dim3(16, NB), 256, 0, stream>>>(hidden, attn, att_out);
    ln_kernel<<<NB, 256, 0, stream>>>(att_out, gamma, beta, out);
}

// Round 2
// 527.260 us; speedup vs baseline: 1.1081x; 1.1081x over previous
//
#include <hip/hip_runtime.h>
#include <hip/hip_bf16.h>

#define HIDDEN 512
#define ATT    128
#define NB     64
#define SL     2048
#define LN_EPS 1e-3f

typedef __attribute__((ext_vector_type(8))) short short8;
typedef __attribute__((ext_vector_type(4))) short short4v;
typedef __attribute__((ext_vector_type(4))) float f32x4;

__device__ __forceinline__ short f2bf(float f) {
    union { float f; unsigned u; } v; v.f = f;
    unsigned r = v.u + 0x7fffu + ((v.u >> 16) & 1u);   // RNE
    return (short)(r >> 16);
}
__device__ __forceinline__ float bf2f(short b) {
    union { unsigned u; float f; } v;
    v.u = ((unsigned)(unsigned short)b) << 16; return v.f;
}
__device__ __forceinline__ float tanh_fast(float x) {
    float cx = fminf(fmaxf(x, -15.f), 15.f);
    float e = __expf(2.f * cx);
    return (e - 1.f) * __builtin_amdgcn_rcpf(e + 1.f);
}

// ---- P1: fused  h_att = bf16(h @ W)  +  ctx column-sum partials -----------
// 1024 blocks x 256 thr; block bx covers rows [bx*128, bx*128+128) of (b,l).
__launch_bounds__(256)
__global__ void p1_gemm_ctx(const float* __restrict__ hidden, const float* __restrict__ W,
                            short* __restrict__ h_att, float* __restrict__ ctx_part) {
    __shared__ char smem[32768];
    short* As    = (short*)smem;             // [128][32] bf16
    short* Ws    = (short*)(smem + 8192);    // [128][32] bf16, n-major
    float* ctx_s = (float*)(smem + 16384);   // [512] fp32 column sums
    short* out_s = (short*)smem;             // [128][128] bf16 (reused after loop)

    int t = threadIdx.x;
    int row0 = blockIdx.x * 128;
    int wave = t >> 6, lane = t & 63, quad = lane >> 4, cb = lane & 15;

    ctx_s[t] = 0.f; ctx_s[t + 256] = 0.f;

    f32x4 acc[2][8];
    #pragma unroll
    for (int mt = 0; mt < 2; ++mt)
        #pragma unroll
        for (int nt = 0; nt < 8; ++nt)
            acc[mt][nt] = (f32x4){0.f, 0.f, 0.f, 0.f};

    for (int k0 = 0; k0 < HIDDEN; k0 += 32) {
        __syncthreads();
        float cx = 0.f, cy = 0.f, cz = 0.f, cw = 0.f;
        // stage A-tile (fp32 -> bf16) and accumulate fp32 column partials
        #pragma unroll
        for (int it = 0; it < 4; ++it) {
            int f = t + it * 256;
            int row = f >> 3, kpos = (f & 7) * 4;
            const float4 g = *(const float4*)(hidden + ((size_t)(row0 + row)) * HIDDEN + k0 + kpos);
            cx += g.x; cy += g.y; cz += g.z; cw += g.w;
            short4v s4 = { f2bf(g.x), f2bf(g.y), f2bf(g.z), f2bf(g.w) };
            *(short4v*)(&As[row * 32 + kpos]) = s4;
        }
        // stage W-tile transposed
        #pragma unroll
        for (int it = 0; it < 4; ++it) {
            int k = (t >> 5) + it * 8;
            int n4 = (t & 31) * 4;
            const float4 g = *(const float4*)(W + (k0 + k) * ATT + n4);
            Ws[(n4 + 0) * 32 + k] = f2bf(g.x);
            Ws[(n4 + 1) * 32 + k] = f2bf(g.y);
            Ws[(n4 + 2) * 32 + k] = f2bf(g.z);
            Ws[(n4 + 3) * 32 + k] = f2bf(g.w);
        }
        __syncthreads();
        // ctx: reduce this chunk's 4-row partials across the wave's stride-8 lanes
        cx += __shfl_xor(cx, 8);  cy += __shfl_xor(cy, 8);  cz += __shfl_xor(cz, 8);  cw += __shfl_xor(cw, 8);
        cx += __shfl_xor(cx, 16); cy += __shfl_xor(cy, 16); cz += __shfl_xor(cz, 16); cw += __shfl_xor(cw, 16);
        cx += __shfl_xor(cx, 32); cy += __shfl_xor(cy, 32); cz += __shfl_xor(cz, 32); cw += __shfl_xor(cw, 32);
        if (lane < 8) {
            atomicAdd(&ctx_s[k0 + lane * 4 + 0], cx);
            atomicAdd(&ctx_s[k0 + lane * 4 + 1], cy);
            atomicAdd(&ctx_s[k0 + lane * 4 + 2], cz);
            atomicAdd(&ctx_s[k0 + lane * 4 + 3], cw);
        }
        short8 a0 = *(const short8*)(&As[(wave * 32 + cb) * 32 + quad * 8]);
        short8 a1 = *(const short8*)(&As[(wave * 32 + 16 + cb) * 32 + quad * 8]);
        #pragma unroll
        for (int nt = 0; nt < 8; ++nt) {
            short8 bf = *(const short8*)(&Ws[(nt * 16 + cb) * 32 + quad * 8]);
            acc[0][nt] = __builtin_amdgcn_mfma_f32_16x16x32_bf16(a0, bf, acc[0][nt], 0, 0, 0);
            acc[1][nt] = __builtin_amdgcn_mfma_f32_16x16x32_bf16(a1, bf, acc[1][nt], 0, 0, 0);
        }
    }
    __syncthreads();
    // flush ctx partials for this block
    ctx_part[(size_t)blockIdx.x * HIDDEN + t]       = ctx_s[t];
    ctx_part[(size_t)blockIdx.x * HIDDEN + 256 + t] = ctx_s[t + 256];
    __syncthreads();
    // dump accumulators to LDS as bf16 (C layout: row = wave*32+mt*16+quad*4+j, col = nt*16+cb)
    #pragma unroll
    for (int mt = 0; mt < 2; ++mt)
        #pragma unroll
        for (int nt = 0; nt < 8; ++nt)
            #pragma unroll
            for (int j = 0; j < 4; ++j)
                out_s[(wave * 32 + mt * 16 + quad * 4 + j) * 128 + nt * 16 + cb] = f2bf(acc[mt][nt][j]);
    __syncthreads();
    // coalesced copy: 128 rows x 128 cols bf16 = 32 KB contiguous
    short8* dst = (short8*)(h_att + (size_t)row0 * ATT);
    const short8* src = (const short8*)out_s;
    #pragma unroll
    for (int i = 0; i < 8; ++i) dst[t + i * 256] = src[t + i * 256];
}

// ---- P2: uatt[b][a] = (sum_chunks ctx_part / SL) . U[:,a] -----------------
__launch_bounds__(256)
__global__ void p2_uatt(const float* __restrict__ ctx_part, const float* __restrict__ U,
                        float* __restrict__ uatt) {
    int b = blockIdx.x, t = threadIdx.x;
    __shared__ float cs[HIDDEN];
    float s0 = 0.f, s1 = 0.f;
    #pragma unroll
    for (int c = 0; c < 16; ++c) {
        size_t base = (size_t)(b * 16 + c) * HIDDEN;
        s0 += ctx_part[base + t];
        s1 += ctx_part[base + 256 + t];
    }
    cs[t] = s0; cs[t + 256] = s1;
    __syncthreads();
    if (t < ATT) {
        float d = 0.f;
        #pragma unroll 8
        for (int h = 0; h < HIDDEN; ++h) d += cs[h] * U[h * ATT + t];
        uatt[b * ATT + t] = d * (1.f / SL);
    }
}

// ---- P3: scores[r] = v . tanh(h_att[r] + uatt[b]) -------------------------
// 2048 blocks x 256 thr; 64 rows/block, 4 lanes per row.
__launch_bounds__(256)
__global__ void p3_scores(const short* __restrict__ h_att, const float* __restrict__ v_a,
                          const float* __restrict__ uatt, float* __restrict__ scores) {
    int t = threadIdx.x, bx = blockIdx.x;
    int row0 = bx * 64, b = bx >> 5;
    __shared__ float v_s[ATT], u_s[ATT];
    if (t < ATT) { v_s[t] = v_a[t]; u_s[t] = uatt[b * ATT + t]; }
    __syncthreads();
    int lr = t >> 2, seg = t & 3;
    const short8* p = (const short8*)(h_att + ((size_t)(row0 + lr)) * ATT + seg * 32);
    float s = 0.f;
    #pragma unroll
    for (int q = 0; q < 4; ++q) {
        short8 h8 = p[q];
        #pragma unroll
        for (int i = 0; i < 8; ++i) {
            int a = seg * 32 + q * 8 + i;
            s += v_s[a] * tanh_fast(bf2f(h8[i]) + u_s[a]);
        }
    }
    s += __shfl_xor(s, 1);
    s += __shfl_xor(s, 2);
    if (seg == 0) scores[row0 + lr] = s;
}

// ---- P4: softmax over L (in place, in d_out's attn region) ----------------
__launch_bounds__(256)
__global__ void p4_softmax(float* __restrict__ attn) {
    int b = blockIdx.x, t = threadIdx.x;
    float* p = attn + b * SL;
    __shared__ float red[256];
    float v[8];
    float m = -1e30f;
    #pragma unroll
    for (int i = 0; i < 8; ++i) { v[i] = p[t + i * 256]; m = fmaxf(m, v[i]); }
    red[t] = m; __syncthreads();
    for (int s = 128; s > 0; s >>= 1) { if (t < s) red[t] = fmaxf(red[t], red[t + s]); __syncthreads(); }
    m = red[0]; __syncthreads();
    float sum = 0.f;
    #pragma unroll
    for (int i = 0; i < 8; ++i) { v[i] = __expf(v[i] - m); sum += v[i]; }
    red[t] = sum; __syncthreads();
    for (int s = 128; s > 0; s >>= 1) { if (t < s) red[t] += red[t + s]; __syncthreads(); }
    float inv = 1.f / red[0];
    #pragma unroll
    for (int i = 0; i < 8; ++i) p[t + i * 256] = v[i] * inv;
}

// ---- P5: attended partials: att_part[c][b][h] = sum_{l in chunk} attn*h ----
__launch_bounds__(256)
__global__ void p5_attended(const float* __restrict__ hidden, const float* __restrict__ attn,
                            float* __restrict__ att_part) {
    int b = blockIdx.y, c = blockIdx.x, t = threadIdx.x;
    __shared__ float w_s[128];
    __shared__ float4 red_s[128];
    if (t < 128) w_s[t] = attn[b * SL + c * 128 + t];
    __syncthreads();
    int cg = t & 127, half = t >> 7;
    const float* hp = hidden + ((size_t)b * SL + c * 128 + half * 64) * HIDDEN + cg * 4;
    float4 a = {0.f, 0.f, 0.f, 0.f};
    #pragma unroll 4
    for (int l = 0; l < 64; ++l) {
        float w = w_s[half * 64 + l];
        const float4 g = *(const float4*)(hp + (size_t)l * HIDDEN);
        a.x += w * g.x; a.y += w * g.y; a.z += w * g.z; a.w += w * g.w;
    }
    if (half) red_s[cg] = a;
    __syncthreads();
    if (!half) {
        float4 r = red_s[cg];
        a.x += r.x; a.y += r.y; a.z += r.z; a.w += r.w;
        *(float4*)(att_part + ((size_t)(c * NB + b)) * HIDDEN + cg * 4) = a;
    }
}

// ---- P6: reduce att_part chunks + LayerNorm -------------------------------
__launch_bounds__(256)
__global__ void p6_ln(const float* __restrict__ att_part, const float* __restrict__ gamma,
                      const float* __restrict__ beta, float* __restrict__ out) {
    int b = blockIdx.x, t = threadIdx.x;
    float x0 = 0.f, x1 = 0.f;
    #pragma unroll
    for (int c = 0; c < 16; ++c) {
        size_t base = (size_t)(c * NB + b) * HIDDEN;
        x0 += att_part[base + t];
        x1 += att_part[base + t + 256];
    }
    __shared__ float rs[256], rq[256];
    rs[t] = x0 + x1; rq[t] = x0 * x0 + x1 * x1;
    __syncthreads();
    for (int s = 128; s > 0; s >>= 1) {
        if (t < s) { rs[t] += rs[t + s]; rq[t] += rq[t + s]; }
        __syncthreads();
    }
    float mean = rs[0] * (1.f / HIDDEN);
    float var = rq[0] * (1.f / HIDDEN) - mean * mean;
    float r = rsqrtf(var + LN_EPS);
    out[b * HIDDEN + t]       = (x0 - mean) * r * gamma[t] + beta[t];
    out[b * HIDDEN + t + 256] = (x1 - mean) * r * gamma[t + 256] + beta[t + 256];
}

extern "C" void kernel_launch(void* const* d_in, const int* in_sizes, int n_in,
                              void* d_out, int out_size, void* d_ws, size_t ws_size,
                              hipStream_t stream) {
    const float* hidden = (const float*)d_in[0];
    const float* W      = (const float*)d_in[1];
    const float* U      = (const float*)d_in[2];
    const float* v_a    = (const float*)d_in[3];
    const float* gamma  = (const float*)d_in[4];
    const float* beta   = (const float*)d_in[5];

    float* out  = (float*)d_out;          // [64][512]
    float* attn = out + NB * HIDDEN;      // [64][2048] scores -> softmax in place

    // ws layout (all buffers fully written before read; no memset needed)
    short* h_att    = (short*)d_ws;                                    // [64*2048][128] bf16, 33.5 MB
    float* ctx_part = (float*)((char*)d_ws + (size_t)NB * SL * ATT * 2);   // [1024][512] fp32, 2 MB
    float* att_part = ctx_part + (size_t)1024 * HIDDEN;                // [16][64][512] fp32, 2 MB
    float* uatt     = att_part + (size_t)16 * NB * HIDDEN;             // [64][128]

    p1_gemm_ctx<<<(NB * SL) / 128, 256, 0, stream>>>(hidden, W, h_att, ctx_part);
    p2_uatt<<<NB, 256, 0, stream>>>(ctx_part, U, uatt);
    p3_scores<<<(NB * SL) / 64, 256, 0, stream>>>(h_att, v_a, uatt, attn);
    p4_softmax<<<NB, 256, 0, stream>>>(attn);
    p5_attended<<<dim3(16, NB), 256, 0, stream>>>(hidden, attn, att_part);
    p6_ln<<<NB, 256, 0, stream>>>(att_part, gamma, beta, out);
}

// Round 4
// 497.973 us; speedup vs baseline: 1.1733x; 1.0588x over previous
//
#include <hip/hip_runtime.h>
#include <hip/hip_bf16.h>

#define HIDDEN 512
#define ATT    128
#define NB     64
#define SL     2048
#define LN_EPS 1e-3f

typedef __attribute__((ext_vector_type(8))) short short8;
typedef __attribute__((ext_vector_type(4))) short short4v;
typedef __attribute__((ext_vector_type(4))) float f32x4;

__device__ __forceinline__ short f2bf(float f) {
    union { float f; unsigned u; } v; v.f = f;
    unsigned r = v.u + 0x7fffu + ((v.u >> 16) & 1u);   // RNE
    return (short)(r >> 16);
}
__device__ __forceinline__ float bf2f(short b) {
    union { unsigned u; float f; } v;
    v.u = ((unsigned)(unsigned short)b) << 16; return v.f;
}
__device__ __forceinline__ float tanh_fast(float x) {
    float cx = fminf(fmaxf(x, -15.f), 15.f);
    float e = __expf(2.f * cx);
    return (e - 1.f) * __builtin_amdgcn_rcpf(e + 1.f);
}

// ---- P0: Wt[a][h] = bf16(W[h][a])  (128 KB, stays L2/L3 resident) ---------
__global__ void p0_wt(const float* __restrict__ W, short* __restrict__ Wt) {
    int idx = blockIdx.x * 256 + threadIdx.x;   // 65536 total
    int a = idx >> 9, h = idx & 511;
    Wt[idx] = f2bf(W[h * ATT + a]);
}

// ---- P1: h_att = bf16(h @ W) + ctx column-sum partials --------------------
// 1024 blocks x 256 thr; block bx covers rows [bx*128, bx*128+128) of (b,l).
// No LDS in the main loop: A-frags direct from global (coalesced, fp32->bf16
// in-register), B-frags direct from L2-resident Wt.
__launch_bounds__(256)
__global__ void p1_gemm_ctx(const float* __restrict__ hidden, const short* __restrict__ Wt,
                            short* __restrict__ h_att, float* __restrict__ ctx_part) {
    __shared__ float ctx_s[HIDDEN];
    __shared__ short out_s[128 * 136];   // padded stride: 136 shorts = 272 B

    int t = threadIdx.x;
    int row0 = blockIdx.x * 128;
    int wave = t >> 6, lane = t & 63, quad = lane >> 4, cb = lane & 15;

    ctx_s[t] = 0.f; ctx_s[t + 256] = 0.f;
    __syncthreads();

    f32x4 acc[2][8];
    #pragma unroll
    for (int mt = 0; mt < 2; ++mt)
        #pragma unroll
        for (int nt = 0; nt < 8; ++nt)
            acc[mt][nt] = (f32x4){0.f, 0.f, 0.f, 0.f};

    const float* aptr0 = hidden + (size_t)(row0 + wave * 32 + cb) * HIDDEN;
    const float* aptr1 = aptr0 + (size_t)16 * HIDDEN;
    const short* bptr  = Wt + (size_t)cb * HIDDEN;

    for (int k0 = 0; k0 < HIDDEN; k0 += 32) {
        int ka = k0 + quad * 8;
        const float4 a0lo = *(const float4*)(aptr0 + ka);
        const float4 a0hi = *(const float4*)(aptr0 + ka + 4);
        const float4 a1lo = *(const float4*)(aptr1 + ka);
        const float4 a1hi = *(const float4*)(aptr1 + ka + 4);

        // B-fragments for this chunk (L2 hits)
        short8 b8[8];
        #pragma unroll
        for (int nt = 0; nt < 8; ++nt)
            b8[nt] = *(const short8*)(bptr + nt * 16 * HIDDEN + ka);

        // ctx column partials: sum this lane's 32-row slice, reduce over cb
        float s[8] = { a0lo.x + a1lo.x, a0lo.y + a1lo.y, a0lo.z + a1lo.z, a0lo.w + a1lo.w,
                       a0hi.x + a1hi.x, a0hi.y + a1hi.y, a0hi.z + a1hi.z, a0hi.w + a1hi.w };
        #pragma unroll
        for (int j = 0; j < 8; ++j) {
            s[j] += __shfl_xor(s[j], 1);
            s[j] += __shfl_xor(s[j], 2);
            s[j] += __shfl_xor(s[j], 4);
            s[j] += __shfl_xor(s[j], 8);
        }
        if (cb == 0) {
            #pragma unroll
            for (int j = 0; j < 8; ++j) atomicAdd(&ctx_s[ka + j], s[j]);
        }

        // A-fragments fp32 -> bf16
        short8 a0 = { f2bf(a0lo.x), f2bf(a0lo.y), f2bf(a0lo.z), f2bf(a0lo.w),
                      f2bf(a0hi.x), f2bf(a0hi.y), f2bf(a0hi.z), f2bf(a0hi.w) };
        short8 a1 = { f2bf(a1lo.x), f2bf(a1lo.y), f2bf(a1lo.z), f2bf(a1lo.w),
                      f2bf(a1hi.x), f2bf(a1hi.y), f2bf(a1hi.z), f2bf(a1hi.w) };

        #pragma unroll
        for (int nt = 0; nt < 8; ++nt) {
            acc[0][nt] = __builtin_amdgcn_mfma_f32_16x16x32_bf16(a0, b8[nt], acc[0][nt], 0, 0, 0);
            acc[1][nt] = __builtin_amdgcn_mfma_f32_16x16x32_bf16(a1, b8[nt], acc[1][nt], 0, 0, 0);
        }
    }
    __syncthreads();
    ctx_part[(size_t)blockIdx.x * HIDDEN + t]       = ctx_s[t];
    ctx_part[(size_t)blockIdx.x * HIDDEN + 256 + t] = ctx_s[t + 256];

    // epilogue: C layout row = wave*32+mt*16+quad*4+j, col = nt*16+cb
    #pragma unroll
    for (int mt = 0; mt < 2; ++mt)
        #pragma unroll
        for (int nt = 0; nt < 8; ++nt)
            #pragma unroll
            for (int j = 0; j < 4; ++j)
                out_s[(wave * 32 + mt * 16 + quad * 4 + j) * 136 + nt * 16 + cb] = f2bf(acc[mt][nt][j]);
    __syncthreads();
    // coalesced copy-out: thread t -> row t>>1, half-row (64 shorts) t&1
    {
        int row = t >> 1, seg = t & 1;
        const short* srcp = out_s + row * 136 + seg * 64;
        short8* dstp = (short8*)(h_att + ((size_t)(row0 + row)) * ATT + seg * 64);
        #pragma unroll
        for (int i = 0; i < 8; ++i) dstp[i] = *(const short8*)(srcp + i * 8);
    }
}

// ---- P2: uatt[b][a] = (sum_chunks ctx_part / SL) . U[:,a] -----------------
__launch_bounds__(256)
__global__ void p2_uatt(const float* __restrict__ ctx_part, const float* __restrict__ U,
                        float* __restrict__ uatt) {
    int b = blockIdx.x, t = threadIdx.x;
    __shared__ float cs[HIDDEN];
    float s0 = 0.f, s1 = 0.f;
    #pragma unroll
    for (int c = 0; c < 16; ++c) {
        size_t base = (size_t)(b * 16 + c) * HIDDEN;
        s0 += ctx_part[base + t];
        s1 += ctx_part[base + 256 + t];
    }
    cs[t] = s0; cs[t + 256] = s1;
    __syncthreads();
    if (t < ATT) {
        float d = 0.f;
        #pragma unroll 8
        for (int h = 0; h < HIDDEN; ++h) d += cs[h] * U[h * ATT + t];
        uatt[b * ATT + t] = d * (1.f / SL);
    }
}

// ---- P3: scores[r] = v . tanh(h_att[r] + uatt[b]) -------------------------
__launch_bounds__(256)
__global__ void p3_scores(const short* __restrict__ h_att, const float* __restrict__ v_a,
                          const float* __restrict__ uatt, float* __restrict__ scores) {
    int t = threadIdx.x, bx = blockIdx.x;
    int row0 = bx * 64, b = bx >> 5;
    __shared__ float v_s[ATT], u_s[ATT];
    if (t < ATT) { v_s[t] = v_a[t]; u_s[t] = uatt[b * ATT + t]; }
    __syncthreads();
    int lr = t >> 2, seg = t & 3;
    const short8* p = (const short8*)(h_att + ((size_t)(row0 + lr)) * ATT + seg * 32);
    float s = 0.f;
    #pragma unroll
    for (int q = 0; q < 4; ++q) {
        short8 h8 = p[q];
        #pragma unroll
        for (int i = 0; i < 8; ++i) {
            int a = seg * 32 + q * 8 + i;
            s += v_s[a] * tanh_fast(bf2f(h8[i]) + u_s[a]);
        }
    }
    s += __shfl_xor(s, 1);
    s += __shfl_xor(s, 2);
    if (seg == 0) scores[row0 + lr] = s;
}

// ---- P4: softmax over L (in place, in d_out's attn region) ----------------
__launch_bounds__(256)
__global__ void p4_softmax(float* __restrict__ attn) {
    int b = blockIdx.x, t = threadIdx.x;
    float* p = attn + b * SL;
    __shared__ float red[256];
    float v[8];
    float m = -1e30f;
    #pragma unroll
    for (int i = 0; i < 8; ++i) { v[i] = p[t + i * 256]; m = fmaxf(m, v[i]); }
    red[t] = m; __syncthreads();
    for (int s = 128; s > 0; s >>= 1) { if (t < s) red[t] = fmaxf(red[t], red[t + s]); __syncthreads(); }
    m = red[0]; __syncthreads();
    float sum = 0.f;
    #pragma unroll
    for (int i = 0; i < 8; ++i) { v[i] = __expf(v[i] - m); sum += v[i]; }
    red[t] = sum; __syncthreads();
    for (int s = 128; s > 0; s >>= 1) { if (t < s) red[t] += red[t + s]; __syncthreads(); }
    float inv = 1.f / red[0];
    #pragma unroll
    for (int i = 0; i < 8; ++i) p[t + i * 256] = v[i] * inv;
}

// ---- P5: attended partials: att_part[c][b][h] = sum_{l in chunk} attn*h ----
__launch_bounds__(256)
__global__ void p5_attended(const float* __restrict__ hidden, const float* __restrict__ attn,
                            float* __restrict__ att_part) {
    int b = blockIdx.y, c = blockIdx.x, t = threadIdx.x;
    __shared__ float w_s[128];
    __shared__ float4 red_s[128];
    if (t < 128) w_s[t] = attn[b * SL + c * 128 + t];
    __syncthreads();
    int cg = t & 127, half = t >> 7;
    const float* hp = hidden + ((size_t)b * SL + c * 128 + half * 64) * HIDDEN + cg * 4;
    float4 a = {0.f, 0.f, 0.f, 0.f};
    #pragma unroll 4
    for (int l = 0; l < 64; ++l) {
        float w = w_s[half * 64 + l];
        const float4 g = *(const float4*)(hp + (size_t)l * HIDDEN);
        a.x += w * g.x; a.y += w * g.y; a.z += w * g.z; a.w += w * g.w;
    }
    if (half) red_s[cg] = a;
    __syncthreads();
    if (!half) {
        float4 r = red_s[cg];
        a.x += r.x; a.y += r.y; a.z += r.z; a.w += r.w;
        *(float4*)(att_part + ((size_t)(c * NB + b)) * HIDDEN + cg * 4) = a;
    }
}

// ---- P6: reduce att_part chunks + LayerNorm -------------------------------
__launch_bounds__(256)
__global__ void p6_ln(const float* __restrict__ att_part, const float* __restrict__ gamma,
                      const float* __restrict__ beta, float* __restrict__ out) {
    int b = blockIdx.x, t = threadIdx.x;
    float x0 = 0.f, x1 = 0.f;
    #pragma unroll
    for (int c = 0; c < 16; ++c) {
        size_t base = (size_t)(c * NB + b) * HIDDEN;
        x0 += att_part[base + t];
        x1 += att_part[base + t + 256];
    }
    __shared__ float rs[256], rq[256];
    rs[t] = x0 + x1; rq[t] = x0 * x0 + x1 * x1;
    __syncthreads();
    for (int s = 128; s > 0; s >>= 1) {
        if (t < s) { rs[t] += rs[t + s]; rq[t] += rq[t + s]; }
        __syncthreads();
    }
    float mean = rs[0] * (1.f / HIDDEN);
    float var = rq[0] * (1.f / HIDDEN) - mean * mean;
    float r = rsqrtf(var + LN_EPS);
    out[b * HIDDEN + t]       = (x0 - mean) * r * gamma[t] + beta[t];
    out[b * HIDDEN + t + 256] = (x1 - mean) * r * gamma[t + 256] + beta[t + 256];
}

extern "C" void kernel_launch(void* const* d_in, const int* in_sizes, int n_in,
                              void* d_out, int out_size, void* d_ws, size_t ws_size,
                              hipStream_t stream) {
    const float* hidden = (const float*)d_in[0];
    const float* W      = (const float*)d_in[1];
    const float* U      = (const float*)d_in[2];
    const float* v_a    = (const float*)d_in[3];
    const float* gamma  = (const float*)d_in[4];
    const float* beta   = (const float*)d_in[5];

    float* out  = (float*)d_out;          // [64][512]
    float* attn = out + NB * HIDDEN;      // [64][2048] scores -> softmax in place

    // ws layout (every buffer fully written before read; no memset needed)
    short* h_att    = (short*)d_ws;                                        // [64*2048][128] bf16
    float* ctx_part = (float*)((char*)d_ws + (size_t)NB * SL * ATT * 2);   // [1024][512]
    float* att_part = ctx_part + (size_t)1024 * HIDDEN;                    // [16][64][512]
    float* uatt     = att_part + (size_t)16 * NB * HIDDEN;                 // [64][128]
    short* Wt       = (short*)(uatt + NB * ATT);                           // [128][512] bf16

    p0_wt<<<256, 256, 0, stream>>>(W, Wt);
    p1_gemm_ctx<<<(NB * SL) / 128, 256, 0, stream>>>(hidden, Wt, h_att, ctx_part);
    p2_uatt<<<NB, 256, 0, stream>>>(ctx_part, U, uatt);
    p3_scores<<<(NB * SL) / 64, 256, 0, stream>>>(h_att, v_a, uatt, attn);
    p4_softmax<<<NB, 256, 0, stream>>>(attn);
    p5_attended<<<dim3(16, NB), 256, 0, stream>>>(hidden, attn, att_part);
    p6_ln<<<NB, 256, 0, stream>>>(att_part, gamma, beta, out);
}